// Round 8
// baseline (488.348 us; speedup 1.0000x reference)
//
#include <hip/hip_runtime.h>

#define N_NODES 10000
#define N_EDGES 640000
#define D_FEAT 128

// ---------------------------------------------------------------------------
// Privatized counting sort: HB blocks each own a contiguous slice of edges.
// ---------------------------------------------------------------------------
#define HB   128                     // hist/reorder blocks
#define HBLK 512
#define EPB  (N_EDGES / HB)          // 5000 edges per block
#define BCS  10016                   // bcnt row stride (ints)

// ws int32-element offsets (no memset needed).
#define WS_BCNT   0                        // HB * BCS = 1282048
#define WS_BSUM   1282048                  // 40
#define WS_START  1282112                  // 10001
#define WS_SORTED 1292160                  // 640000
#define WS_AGG    1932160                  // float[10000*128]

// ---------------------------------------------------------------------------
// K1: per-block LDS histogram of this block's 5000-edge slice -> bcnt[bid][*].
// ---------------------------------------------------------------------------
__global__ __launch_bounds__(HBLK) void hist_kernel(
        const int* __restrict__ recv, int* __restrict__ bcnt) {
    __shared__ int h[N_NODES];               // 40 KB
    for (int i = threadIdx.x; i < N_NODES; i += HBLK) h[i] = 0;
    __syncthreads();
    const int4* r4 = (const int4*)(recv + blockIdx.x * EPB);
    for (int i = threadIdx.x; i < EPB / 4; i += HBLK) {
        const int4 r = r4[i];
        atomicAdd(&h[r.x], 1);               // ds_add (LDS scope)
        atomicAdd(&h[r.y], 1);
        atomicAdd(&h[r.z], 1);
        atomicAdd(&h[r.w], 1);
    }
    __syncthreads();
    int* dst = bcnt + blockIdx.x * BCS;
    for (int i = threadIdx.x; i < N_NODES; i += HBLK) dst[i] = h[i];
}

// ---------------------------------------------------------------------------
// K2: node-parallel. Exclusive prefix over HB block counts (in place),
// node total -> in-block scan -> block-local start[] + per-block sums.
// ---------------------------------------------------------------------------
__global__ __launch_bounds__(256) void scan1_kernel(
        int* __restrict__ bcnt, int* __restrict__ start, int* __restrict__ bsum) {
    __shared__ int s_w[4];
    const int tid = threadIdx.x;
    const int n   = blockIdx.x * 256 + tid;
    const bool ok = (n < N_NODES);

    int tot = 0;
    if (ok) {
        int run = 0;
        #pragma unroll 16
        for (int b = 0; b < HB; ++b) {
            int* p = bcnt + b * BCS + n;     // coalesced across lanes
            const int c = *p;
            *p = run;
            run += c;
        }
        tot = run;
    }
    const int lane = tid & 63;
    const int wave = tid >> 6;
    int x = tot;
    #pragma unroll
    for (int off = 1; off < 64; off <<= 1) {
        int t = __shfl_up(x, off, 64);
        if (lane >= off) x += t;
    }
    if (lane == 63) s_w[wave] = x;
    __syncthreads();
    int woff = 0;
    #pragma unroll
    for (int k = 0; k < 3; ++k) woff += (k < wave) ? s_w[k] : 0;
    if (ok) start[n] = woff + x - tot;
    if (tid == 0) bsum[blockIdx.x] = s_w[0] + s_w[1] + s_w[2] + s_w[3];
}

// ---------------------------------------------------------------------------
// K3: add cross-block offsets into start[].
// ---------------------------------------------------------------------------
__global__ __launch_bounds__(256) void scan2_kernel(
        const int* __restrict__ bsum, int* __restrict__ start) {
    __shared__ int s_boff;
    const int tid = threadIdx.x;
    if (tid == 0) {
        int acc = 0;
        for (int k = 0; k < (int)blockIdx.x; ++k) acc += bsum[k];
        s_boff = acc;
        if (blockIdx.x == 0) start[N_NODES] = N_EDGES;
    }
    __syncthreads();
    const int n = blockIdx.x * 256 + tid;
    if (n < N_NODES) start[n] += s_boff;
}

// ---------------------------------------------------------------------------
// K4: reorder via LDS cursors (ds_add_rtn). No global atomics.
// ---------------------------------------------------------------------------
__global__ __launch_bounds__(HBLK) void reorder_kernel(
        const int* __restrict__ recv, const int* __restrict__ bcnt,
        const int* __restrict__ start, int* __restrict__ sorted) {
    __shared__ int cur[N_NODES];             // 40 KB
    const int* rel = bcnt + blockIdx.x * BCS;
    for (int i = threadIdx.x; i < N_NODES; i += HBLK)
        cur[i] = start[i] + rel[i];
    __syncthreads();
    const int ebase = blockIdx.x * EPB;
    const int4* r4 = (const int4*)(recv + ebase);
    for (int i = threadIdx.x; i < EPB / 4; i += HBLK) {
        const int4 r = r4[i];
        const int e = ebase + i * 4;
        sorted[atomicAdd(&cur[r.x], 1)] = e + 0;
        sorted[atomicAdd(&cur[r.y], 1)] = e + 1;
        sorted[atomicAdd(&cur[r.z], 1)] = e + 2;
        sorted[atomicAdd(&cur[r.w], 1)] = e + 3;
    }
}

// ---------------------------------------------------------------------------
// K5: gather-sum, ONE WAVE PER NODE. Half-wave h covers rows s+h, s+h+2, ...
// (lane&31 = float4 chunk). 4 rows in flight + next-4 index prefetch ->
// ~4 KB outstanding per wave; low VGPR -> full occupancy for latency hiding.
// ---------------------------------------------------------------------------
__global__ __launch_bounds__(256) void gather_kernel(
        const float4* __restrict__ edge_feat4,
        const int* __restrict__ sorted_eid,
        const int* __restrict__ start,
        float4* __restrict__ agg4) {
    const int tid  = threadIdx.x;
    const int n    = blockIdx.x * 4 + (tid >> 6);   // wave id == node
    const int lane = tid & 63;
    const int half = lane >> 5;
    const int l    = lane & 31;

    const int s = start[n];
    const int e = start[n + 1];
    float4 acc = {0.f, 0.f, 0.f, 0.f};

    int i = s + half;
    if (i + 6 < e) {
        int e0 = sorted_eid[i];
        int e1 = sorted_eid[i + 2];
        int e2 = sorted_eid[i + 4];
        int e3 = sorted_eid[i + 6];
        i += 8;
        while (i + 6 < e) {
            const int f0 = sorted_eid[i];
            const int f1 = sorted_eid[i + 2];
            const int f2 = sorted_eid[i + 4];
            const int f3 = sorted_eid[i + 6];
            const float4 v0 = edge_feat4[(long)e0 * 32 + l];
            const float4 v1 = edge_feat4[(long)e1 * 32 + l];
            const float4 v2 = edge_feat4[(long)e2 * 32 + l];
            const float4 v3 = edge_feat4[(long)e3 * 32 + l];
            acc.x += (v0.x + v1.x) + (v2.x + v3.x);
            acc.y += (v0.y + v1.y) + (v2.y + v3.y);
            acc.z += (v0.z + v1.z) + (v2.z + v3.z);
            acc.w += (v0.w + v1.w) + (v2.w + v3.w);
            e0 = f0; e1 = f1; e2 = f2; e3 = f3;
            i += 8;
        }
        const float4 v0 = edge_feat4[(long)e0 * 32 + l];
        const float4 v1 = edge_feat4[(long)e1 * 32 + l];
        const float4 v2 = edge_feat4[(long)e2 * 32 + l];
        const float4 v3 = edge_feat4[(long)e3 * 32 + l];
        acc.x += (v0.x + v1.x) + (v2.x + v3.x);
        acc.y += (v0.y + v1.y) + (v2.y + v3.y);
        acc.z += (v0.z + v1.z) + (v2.z + v3.z);
        acc.w += (v0.w + v1.w) + (v2.w + v3.w);
    }
    for (; i < e; i += 2) {
        const float4 v = edge_feat4[(long)sorted_eid[i] * 32 + l];
        acc.x += v.x; acc.y += v.y; acc.z += v.z; acc.w += v.w;
    }

    float4 o;
    o.x = acc.x + __shfl(acc.x, lane + 32, 64);
    o.y = acc.y + __shfl(acc.y, lane + 32, 64);
    o.z = acc.z + __shfl(acc.z, lane + 32, 64);
    o.w = acc.w + __shfl(acc.w, lane + 32, 64);
    if (half == 0)
        agg4[(long)n * 32 + l] = o;
}

// ---------------------------------------------------------------------------
// K6: register-tiled GEMM: out[10000,128] = [node||agg][10000,256] @ W + b
// ---------------------------------------------------------------------------
__global__ __launch_bounds__(256) void gemm_kernel(
        const float* __restrict__ node_feat,
        const float* __restrict__ agg,
        const float* __restrict__ W,
        const float* __restrict__ b,
        float* __restrict__ out) {
    __shared__ __align__(16) float As[32][68];
    __shared__ __align__(16) float Bs[32][64];
    const int tid = threadIdx.x;
    const int tx = tid & 15;
    const int ty = tid >> 4;
    const int m0 = blockIdx.x * 64;
    const int n0 = blockIdx.y * 64;

    float acc[4][4] = {};

    for (int kt = 0; kt < 2 * D_FEAT; kt += 32) {
        const float* src = (kt < D_FEAT) ? (node_feat + kt) : (agg + (kt - D_FEAT));
        {
            const int r  = tid >> 3;
            const int c4 = tid & 7;
            #pragma unroll
            for (int p = 0; p < 2; ++p) {
                int row = m0 + p * 32 + r;
                row = (row < N_NODES) ? row : (N_NODES - 1);
                const float4 a4 = *(const float4*)(src + (long)row * D_FEAT + c4 * 4);
                As[c4 * 4 + 0][p * 32 + r] = a4.x;
                As[c4 * 4 + 1][p * 32 + r] = a4.y;
                As[c4 * 4 + 2][p * 32 + r] = a4.z;
                As[c4 * 4 + 3][p * 32 + r] = a4.w;
            }
        }
        {
            const int r  = tid >> 4;
            const int c4 = tid & 15;
            #pragma unroll
            for (int p = 0; p < 2; ++p) {
                const int row = kt + p * 16 + r;
                *(float4*)&Bs[p * 16 + r][c4 * 4] =
                    *(const float4*)(W + (long)row * D_FEAT + n0 + c4 * 4);
            }
        }
        __syncthreads();
        #pragma unroll
        for (int kk = 0; kk < 32; ++kk) {
            const float4 a4 = *(const float4*)&As[kk][ty * 4];
            const float4 b4 = *(const float4*)&Bs[kk][tx * 4];
            acc[0][0] += a4.x * b4.x; acc[0][1] += a4.x * b4.y;
            acc[0][2] += a4.x * b4.z; acc[0][3] += a4.x * b4.w;
            acc[1][0] += a4.y * b4.x; acc[1][1] += a4.y * b4.y;
            acc[1][2] += a4.y * b4.z; acc[1][3] += a4.y * b4.w;
            acc[2][0] += a4.z * b4.x; acc[2][1] += a4.z * b4.y;
            acc[2][2] += a4.z * b4.z; acc[2][3] += a4.z * b4.w;
            acc[3][0] += a4.w * b4.x; acc[3][1] += a4.w * b4.y;
            acc[3][2] += a4.w * b4.z; acc[3][3] += a4.w * b4.w;
        }
        __syncthreads();
    }

    const float4 bias = *(const float4*)(b + n0 + tx * 4);
    #pragma unroll
    for (int i2 = 0; i2 < 4; ++i2) {
        const int row = m0 + ty * 4 + i2;
        if (row < N_NODES) {
            float4 o;
            o.x = acc[i2][0] + bias.x;
            o.y = acc[i2][1] + bias.y;
            o.z = acc[i2][2] + bias.z;
            o.w = acc[i2][3] + bias.w;
            *(float4*)(out + (long)row * D_FEAT + n0 + tx * 4) = o;
        }
    }
}

// ---------------------------------------------------------------------------
extern "C" void kernel_launch(void* const* d_in, const int* in_sizes, int n_in,
                              void* d_out, int out_size, void* d_ws, size_t ws_size,
                              hipStream_t stream) {
    const float* edge_feat = (const float*)d_in[0];
    const float* node_feat = (const float*)d_in[1];
    const int*   recv      = (const int*)d_in[2];
    const float* W         = (const float*)d_in[3];
    const float* b         = (const float*)d_in[4];
    float* out = (float*)d_out;

    int* wsi    = (int*)d_ws;
    int* bcnt   = wsi + WS_BCNT;
    int* bsum   = wsi + WS_BSUM;
    int* startp = wsi + WS_START;
    int* sorted = wsi + WS_SORTED;
    float* agg  = (float*)(wsi + WS_AGG);

    hist_kernel<<<HB, HBLK, 0, stream>>>(recv, bcnt);
    scan1_kernel<<<(N_NODES + 255) / 256, 256, 0, stream>>>(bcnt, startp, bsum);
    scan2_kernel<<<(N_NODES + 255) / 256, 256, 0, stream>>>(bsum, startp);
    reorder_kernel<<<HB, HBLK, 0, stream>>>(recv, bcnt, startp, sorted);
    gather_kernel<<<N_NODES / 4, 256, 0, stream>>>(
        (const float4*)edge_feat, sorted, startp, (float4*)agg);
    dim3 ggrid((N_NODES + 63) / 64, D_FEAT / 64);
    gemm_kernel<<<ggrid, 256, 0, stream>>>(node_feat, agg, W, b, out);
}